// Round 2
// baseline (1152.732 us; speedup 1.0000x reference)
//
#include <hip/hip_runtime.h>
#include <cstdint>

typedef _Float16 f16;
typedef __attribute__((ext_vector_type(8))) _Float16 f16x8;
typedef __attribute__((ext_vector_type(4))) _Float16 f16x4;
typedef __attribute__((ext_vector_type(4))) float f32x4;

#define NROIS 4096
#define NBANK 8192
#define DIMIN 2048
#define LAT   1024

__device__ __forceinline__ void gload16(const f16* g, f16* l) {
  __builtin_amdgcn_global_load_lds(
      (const __attribute__((address_space(1))) void*)g,
      (__attribute__((address_space(3))) void*)l, 16, 0, 0);
}

__device__ __forceinline__ f32x4 mfma16(f16x8 a, f16x8 b, f32x4 c) {
  return __builtin_amdgcn_mfma_f32_16x16x32_f16(a, b, c, 0, 0, 0);
}

// C = A @ B^T.  A [M,K] f16 row-major (lda), B [N,K] f16 row-major (ldb).
// Tile 128x128, BK=32, 256 threads (4 waves 2x2), 4x4 16x16x32 frags/wave.
// MODE 0: C f16 = acc + bias[col]
// MODE 1: C f16 = exp(acc*scale); den[row] += row-sum (atomic)
// MODE 2: C f32 atomicAdd(acc)            (split-K partial accumulate)
// MODE 3: C f32 = acc + bias[col]
template<int MODE>
__global__ __launch_bounds__(256)
void gemm_bt(const f16* __restrict__ A, const f16* __restrict__ B,
             void* __restrict__ Cp, int K, int lda, int ldb, int ldc,
             const float* __restrict__ bias, float* __restrict__ den,
             float scale)
{
  __shared__ __align__(16) f16 As[128 * 32];
  __shared__ __align__(16) f16 Bs[128 * 32];
  const int t    = threadIdx.x;
  const int w    = t >> 6;
  const int lane = t & 63;
  const int r0   = blockIdx.y * 128;
  const int c0   = blockIdx.x * 128;
  const int koff = blockIdx.z * K;   // split-K offset (z=0 when no split)

  const int lr = lane >> 2;          // staging: row within 16-row chunk
  const int lc = (lane & 3) * 8;     // staging: col (elements)

  f32x4 acc[4][4];
#pragma unroll
  for (int m = 0; m < 4; ++m)
#pragma unroll
    for (int n = 0; n < 4; ++n)
      acc[m][n] = (f32x4)0.0f;

  const int wr = (w >> 1) * 64;      // wave row offset in tile
  const int wc = (w & 1) * 64;       // wave col offset in tile
  const int fr = lane & 15;          // fragment row
  const int fs = (lane >> 4) * 8;    // fragment k-segment

  for (int k0 = 0; k0 < K; k0 += 32) {
#pragma unroll
    for (int i = 0; i < 2; ++i) {
      const int ch = i * 4 + w;      // 8 chunks of 16 rows each per matrix
      gload16(A + (size_t)(r0 + ch * 16 + lr) * lda + (koff + k0 + lc),
              &As[ch * 512 + lane * 8]);
      gload16(B + (size_t)(c0 + ch * 16 + lr) * ldb + (koff + k0 + lc),
              &Bs[ch * 512 + lane * 8]);
    }
    __syncthreads();

    f16x8 af[4], bfv[4];
#pragma unroll
    for (int m = 0; m < 4; ++m)
      af[m] = *(const f16x8*)&As[(wr + m * 16 + fr) * 32 + fs];
#pragma unroll
    for (int n = 0; n < 4; ++n)
      bfv[n] = *(const f16x8*)&Bs[(wc + n * 16 + fr) * 32 + fs];
#pragma unroll
    for (int m = 0; m < 4; ++m)
#pragma unroll
      for (int n = 0; n < 4; ++n)
        acc[m][n] = mfma16(af[m], bfv[n], acc[m][n]);
    __syncthreads();
  }

  // Epilogue. C/D layout: col = lane&15, row = (lane>>4)*4 + reg.
  const int cr = (lane >> 4) * 4;
  const int cc = lane & 15;

  if (MODE == 0) {
    f16* C = (f16*)Cp;
#pragma unroll
    for (int m = 0; m < 4; ++m)
#pragma unroll
      for (int j = 0; j < 4; ++j) {
        const int r = r0 + wr + m * 16 + cr + j;
#pragma unroll
        for (int n = 0; n < 4; ++n) {
          const int c = c0 + wc + n * 16 + cc;
          C[(size_t)r * ldc + c] = (f16)(acc[m][n][j] + bias[c]);
        }
      }
  } else if (MODE == 1) {
    f16* C = (f16*)Cp;
#pragma unroll
    for (int m = 0; m < 4; ++m)
#pragma unroll
      for (int j = 0; j < 4; ++j) {
        const int r = r0 + wr + m * 16 + cr + j;
        float rs = 0.0f;
#pragma unroll
        for (int n = 0; n < 4; ++n) {
          const int c = c0 + wc + n * 16 + cc;
          float e = __expf(acc[m][n][j] * scale);
          rs += e;
          C[(size_t)r * ldc + c] = (f16)e;
        }
        rs += __shfl_xor(rs, 1);
        rs += __shfl_xor(rs, 2);
        rs += __shfl_xor(rs, 4);
        rs += __shfl_xor(rs, 8);
        if (cc == 0) unsafeAtomicAdd(&den[r], rs);
      }
  } else if (MODE == 2) {
    float* C = (float*)Cp;
#pragma unroll
    for (int m = 0; m < 4; ++m)
#pragma unroll
      for (int j = 0; j < 4; ++j) {
        const int r = r0 + wr + m * 16 + cr + j;
#pragma unroll
        for (int n = 0; n < 4; ++n) {
          const int c = c0 + wc + n * 16 + cc;
          unsafeAtomicAdd(&C[(size_t)r * ldc + c], acc[m][n][j]);
        }
      }
  } else {
    float* C = (float*)Cp;
#pragma unroll
    for (int m = 0; m < 4; ++m)
#pragma unroll
      for (int j = 0; j < 4; ++j) {
        const int r = r0 + wr + m * 16 + cr + j;
#pragma unroll
        for (int n = 0; n < 4; ++n) {
          const int c = c0 + wc + n * 16 + cc;
          C[(size_t)r * ldc + c] = acc[m][n][j] + bias[c];
        }
      }
  }
}

// f32 -> f16 vectorized convert (n4 = n/4)
__global__ __launch_bounds__(256)
void cvt_f16(const float* __restrict__ in, f16* __restrict__ out, int n4) {
  int i = blockIdx.x * 256 + threadIdx.x;
  const int stride = gridDim.x * 256;
  for (; i < n4; i += stride) {
    float4 v = ((const float4*)in)[i];
    f16x4 o = { (f16)v.x, (f16)v.y, (f16)v.z, (f16)v.w };
    ((f16x4*)out)[i] = o;
  }
}

// concat biases into f32 scratch + zero den. grid 32 x 256 (8192 threads)
__global__ __launch_bounds__(256)
void init_misc(const float* __restrict__ bc1, const float* __restrict__ bd1,
               const float* __restrict__ bc2, const float* __restrict__ bc3,
               const float* __restrict__ bd2, const float* __restrict__ bd3,
               float* __restrict__ biasq, float* __restrict__ biaskv,
               float* __restrict__ den)
{
  const int i = blockIdx.x * 256 + threadIdx.x;
  if (i < 1024) {
    biasq[i]         = bc1[i];
    biasq[1024 + i]  = bd1[i];
    biaskv[i]        = bc2[i];
    biaskv[1024 + i] = bc3[i];
    biaskv[2048 + i] = bd2[i];
    biaskv[3072 + i] = bd3[i];
  }
  den[i] = 0.0f;
}

__global__ __launch_bounds__(256)
void zero_f32(float4* __restrict__ p, int n4) {
  int i = blockIdx.x * 256 + threadIdx.x;
  const int stride = gridDim.x * 256;
  float4 z; z.x = 0.f; z.y = 0.f; z.z = 0.f; z.w = 0.f;
  for (; i < n4; i += stride) p[i] = z;
}

__global__ __launch_bounds__(256)
void fill_f32(float* __restrict__ p, float v, int n) {
  int i = blockIdx.x * 256 + threadIdx.x;
  const int stride = gridDim.x * 256;
  for (; i < n; i += stride) p[i] = v;
}

// vT[c][r] = kv[r][col_ofs + c]   (r<8192, c<1024), 64x64 LDS tiles
__global__ __launch_bounds__(256)
void transpose_v(const f16* __restrict__ kv, f16* __restrict__ vT, int col_ofs) {
  __shared__ f16 tile[64][66];
  const int r0 = blockIdx.x * 64;
  const int c0 = blockIdx.y * 64;
  const int tx = threadIdx.x;   // 0..63
  const int ty = threadIdx.y;   // 0..3
  for (int i = ty; i < 64; i += 4)
    tile[i][tx] = kv[(size_t)(r0 + i) * 4096 + col_ofs + c0 + tx];
  __syncthreads();
  for (int i = ty; i < 64; i += 4)
    vT[(size_t)(c0 + i) * NBANK + r0 + tx] = tile[tx][i];
}

// cpair = (f1/den1)*(f2/den2); LayerNorm over 1024; PReLU; -> x f16
__global__ __launch_bounds__(256)
void gate_ln(const float* __restrict__ f1, const float* __restrict__ f2,
             const float* __restrict__ den,
             const float* __restrict__ lnw, const float* __restrict__ lnb,
             const float* __restrict__ pa, f16* __restrict__ x)
{
  const int row = blockIdx.x;
  const int t   = threadIdx.x;
  const int lane = t & 63, w = t >> 6;
  const float inv1 = 1.0f / den[row];
  const float inv2 = 1.0f / den[NROIS + row];
  const float4 a = ((const float4*)(f1 + (size_t)row * LAT))[t];
  const float4 b = ((const float4*)(f2 + (size_t)row * LAT))[t];
  float c[4] = { a.x * b.x * inv1 * inv2, a.y * b.y * inv1 * inv2,
                 a.z * b.z * inv1 * inv2, a.w * b.w * inv1 * inv2 };
  float s = c[0] + c[1] + c[2] + c[3];
  float q = c[0]*c[0] + c[1]*c[1] + c[2]*c[2] + c[3]*c[3];
#pragma unroll
  for (int m = 1; m < 64; m <<= 1) {
    s += __shfl_xor(s, m);
    q += __shfl_xor(q, m);
  }
  __shared__ float red[8];
  if (lane == 0) { red[w] = s; red[4 + w] = q; }
  __syncthreads();
  s = red[0] + red[1] + red[2] + red[3];
  q = red[4] + red[5] + red[6] + red[7];
  const float mu  = s * (1.0f / LAT);
  const float var = q * (1.0f / LAT) - mu * mu;
  const float rs  = rsqrtf(var + 1e-5f);
  const float slope = pa[0];
  f16x4 o;
#pragma unroll
  for (int j = 0; j < 4; ++j) {
    float xv = (c[j] - mu) * rs * lnw[t * 4 + j] + lnb[t * 4 + j];
    xv = (xv >= 0.0f) ? xv : slope * xv;
    o[j] = (f16)xv;
  }
  ((f16x4*)(x + (size_t)row * LAT))[t] = o;
}

extern "C" void kernel_launch(void* const* d_in, const int* in_sizes, int n_in,
                              void* d_out, int out_size, void* d_ws, size_t ws_size,
                              hipStream_t stream) {
  const float* feat = (const float*)d_in[0];
  const float* bank = (const float*)d_in[1];
  const float* Wc1  = (const float*)d_in[2];
  const float* bc1  = (const float*)d_in[3];
  const float* Wc2  = (const float*)d_in[4];
  const float* bc2  = (const float*)d_in[5];
  const float* Wc3  = (const float*)d_in[6];
  const float* bc3  = (const float*)d_in[7];
  const float* Wd1  = (const float*)d_in[8];
  const float* bd1  = (const float*)d_in[9];
  const float* Wd2  = (const float*)d_in[10];
  const float* bd2  = (const float*)d_in[11];
  const float* Wd3  = (const float*)d_in[12];
  const float* bd3  = (const float*)d_in[13];
  const float* lnw  = (const float*)d_in[14];
  const float* lnb  = (const float*)d_in[15];
  const float* pa   = (const float*)d_in[16];
  const float* Wffn = (const float*)d_in[17];
  const float* bffn = (const float*)d_in[18];

  const size_t MBy = 1ull << 20;

  // ws_size guard: if scratch is too small, emit sentinel 12345.0 and bail.
  if (ws_size < 133 * MBy) {
    fill_f32<<<dim3(2048), dim3(256), 0, stream>>>((float*)d_out, 12345.0f, out_size);
    return;
  }

  char* ws = (char*)d_ws;
  // ws layout (lifetime-aliased), peak 132MB + 56KB:
  f16*   kvb  = (f16*)(ws);              // [0,64M)    kv = k1|v1|k2|v2, persistent
  f16*   q12  = (f16*)(ws + 64 * MBy);   // [64,80M)   q1|q2, persistent
  f16*   Wfb  = (f16*)(ws + 80 * MBy);   // [80,84M)   Wffn f16, persistent
  f16*   WQ   = (f16*)(ws + 84 * MBy);   // [84,92M)   phase1 only
  f16*   xbuf = (f16*)(ws + 84 * MBy);   // [84,92M)   written after vT dead
  f16*   vTb  = (f16*)(ws + 84 * MBy);   // [84,100M)  per-branch, phase3
  f16*   BB   = (f16*)(ws + 92 * MBy);   // [92,124M)  bank f16, phase1 only
  f16*   Eb   = (f16*)(ws + 100 * MBy);  // [100,132M) E chunk [2048x8192]
  float* biasq  = (float*)(ws + 132 * MBy);          // 8KB
  float* biaskv = (float*)(ws + 132 * MBy + 8192);   // 16KB
  float* den    = (float*)(ws + 132 * MBy + 24576);  // 32KB
  // d_out doubles as scratch until the final GEMM overwrites it:
  f16*   WKV = (f16*)d_out;                       // [0,16M)  phase1
  f16*   FB  = (f16*)((char*)d_out + 16 * MBy);   // [16,32M) phase1
  float* f1  = (float*)d_out;                     // [0,16M)  phase3
  float* f2  = (float*)((char*)d_out + 16 * MBy); // [16,32M) phase3

  // 1. biases + den
  init_misc<<<dim3(32), dim3(256), 0, stream>>>(bc1, bd1, bc2, bc3, bd2, bd3,
                                                biasq, biaskv, den);

  // 2. f32 -> f16 conversions
  auto cvt = [&](const float* in, f16* out, size_t n) {
    int n4 = (int)(n / 4);
    int blocks = (n4 + 255) / 256;
    if (blocks > 2048) blocks = 2048;
    cvt_f16<<<dim3(blocks), dim3(256), 0, stream>>>(in, out, n4);
  };
  cvt(Wc1, WQ,                          (size_t)1024 * 2048);
  cvt(Wd1, WQ + (size_t)1024 * 2048,    (size_t)1024 * 2048);
  cvt(feat, FB, (size_t)NROIS * DIMIN);
  cvt(Wc2, WKV,                         (size_t)1024 * 2048);
  cvt(Wc3, WKV + (size_t)1024 * 2048,   (size_t)1024 * 2048);
  cvt(Wd2, WKV + (size_t)2048 * 2048,   (size_t)1024 * 2048);
  cvt(Wd3, WKV + (size_t)3072 * 2048,   (size_t)1024 * 2048);
  cvt(bank, BB, (size_t)NBANK * DIMIN);
  cvt(Wffn, Wfb, (size_t)2048 * 1024);

  // 3. q12 = FB @ WQ^T + biasq      [4096,2048] f16
  gemm_bt<0><<<dim3(16, 32, 1), 256, 0, stream>>>(
      FB, WQ, q12, 2048, 2048, 2048, 2048, biasq, nullptr, 0.0f);
  // 4. kv = BB @ WKV^T + biaskv     [8192,4096] f16 (k1|v1|k2|v2)
  gemm_bt<0><<<dim3(32, 64, 1), 256, 0, stream>>>(
      BB, WKV, kvb, 2048, 2048, 2048, 4096, biaskv, nullptr, 0.0f);

  // 5. zero f1,f2 (the whole d_out, 32MB) — FB/WKV dead now
  zero_f32<<<dim3(2048), dim3(256), 0, stream>>>((float4*)d_out, (32 * (int)MBy) / 16);

  // 6. attention, branch-sequenced, E chunked by 2048 rows
  const float scl = 0.03125f;  // 1/sqrt(1024)
  for (int b = 0; b < 2; ++b) {
    transpose_v<<<dim3(128, 16, 1), dim3(64, 4), 0, stream>>>(
        kvb, vTb, 1024 + b * 2048);
    float* fb = b ? f2 : f1;
    for (int chunk = 0; chunk < 2; ++chunk) {
      // E = exp(q_b[chunk] @ k_b^T / 32)  [2048,8192] f16 + row sums
      gemm_bt<1><<<dim3(64, 16, 1), 256, 0, stream>>>(
          q12 + (size_t)chunk * 2048 * 2048 + b * 1024, kvb + b * 2048,
          Eb, 1024, 2048, 4096, 8192,
          nullptr, den + b * NROIS + chunk * 2048, scl);
      // f_b[chunk] += E @ vT^T  (split-K=4, f32 atomics)  [2048,1024]
      gemm_bt<2><<<dim3(8, 16, 4), 256, 0, stream>>>(
          Eb, vTb, fb + (size_t)chunk * 2048 * 1024, 2048, 8192, 8192, 1024,
          nullptr, nullptr, 0.0f);
    }
  }

  // 7. gate + LayerNorm + PReLU -> x f16 [4096,1024]  (over dead vT region)
  gate_ln<<<dim3(NROIS), dim3(256), 0, stream>>>(f1, f2, den, lnw, lnb, pa, xbuf);

  // 8. out = x @ Wffn^T + bffn  [4096,2048] f32  (overwrites all of d_out)
  gemm_bt<3><<<dim3(16, 32, 1), 256, 0, stream>>>(
      xbuf, Wfb, (float*)d_out, 1024, 1024, 1024, 2048, bffn, nullptr, 0.0f);
}

// Round 3
// 1102.584 us; speedup vs baseline: 1.0455x; 1.0455x over previous
//
#include <hip/hip_runtime.h>
#include <cstdint>

typedef _Float16 f16;
typedef __attribute__((ext_vector_type(8))) _Float16 f16x8;
typedef __attribute__((ext_vector_type(4))) _Float16 f16x4;
typedef __attribute__((ext_vector_type(4))) float f32x4;

#define NROIS 4096
#define NBANK 8192
#define DIMIN 2048
#define LAT   1024

__device__ __forceinline__ void gload16(const f16* g, f16* l) {
  __builtin_amdgcn_global_load_lds(
      (const __attribute__((address_space(1))) void*)g,
      (__attribute__((address_space(3))) void*)l, 16, 0, 0);
}

__device__ __forceinline__ f32x4 mfma16(f16x8 a, f16x8 b, f32x4 c) {
  return __builtin_amdgcn_mfma_f32_16x16x32_f16(a, b, c, 0, 0, 0);
}

// ---------------------------------------------------------------------------
// 256x256 tile, BK=32, 512 threads (8 waves 2Mx4N), 3-slot LDS rotation,
// counted vmcnt(4) at tile boundaries (T3+T4), setprio (T5), XCD swizzle (T1).
// Safety: tile t reads slot t%3; tile t+2 stages into slot (t+2)%3, whose last
// reader was tile t-1 (already barrier-complete) -> no clobber race.
// MODE 0: C f16 = acc + bias[col]
// MODE 1: C f16 = exp(acc*scale); den[row] += row-sum (atomic)
// MODE 2: C f32 atomicAdd(acc)  (split-K via blockIdx.z)
// ---------------------------------------------------------------------------
template<int MODE>
__global__ __launch_bounds__(512, 2)
void gemm2(const f16* __restrict__ A, const f16* __restrict__ B,
           void* __restrict__ Cp, int K, int lda, int ldb, int ldc,
           const float* __restrict__ bias, float* __restrict__ den,
           float scale)
{
  extern __shared__ __align__(16) f16 lds[];   // [3][8192] A | [3][8192] B
  f16* As = lds;
  f16* Bs = lds + 3 * 8192;

  const int tid  = threadIdx.x;
  const int w    = tid >> 6;
  const int lane = tid & 63;

  // XCD-aware swizzle (requires gx*gy % 8 == 0 -- all our launches comply)
  const int gx = gridDim.x;
  const int nwg = gx * gridDim.y;
  int id = blockIdx.y * gx + blockIdx.x;
  id = (id & 7) * (nwg >> 3) + (id >> 3);
  const int bx = id % gx, by = id / gx;

  const int r0   = by * 256;
  const int c0   = bx * 256;
  const int koff = blockIdx.z * K;

  // staging addresses: thread covers row (tid>>2), 16B col chunk (tid&3)
  const f16* gA = A + (size_t)(r0 + (tid >> 2)) * lda + koff + (tid & 3) * 8;
  const f16* gB = B + (size_t)(c0 + (tid >> 2)) * ldb + koff + (tid & 3) * 8;
  const size_t lda128 = (size_t)128 * lda;
  const size_t ldb128 = (size_t)128 * ldb;
  f16* dA = As + tid * 8;   // + slot*8192 (+4096 for rows 128..255)
  f16* dB = Bs + tid * 8;

  // fragment read offsets (A row: wrow+m*16+fr, col seg (lane>>4)*8)
  const int aoff = ((w >> 2) * 128 + (lane & 15)) * 32 + (lane >> 4) * 8;
  const int boff = ((w & 3) * 64 + (lane & 15)) * 32 + (lane >> 4) * 8;

  f32x4 acc[8][4];
#pragma unroll
  for (int m = 0; m < 8; ++m)
#pragma unroll
    for (int n = 0; n < 4; ++n)
      acc[m][n] = (f32x4)0.0f;

  const int nt = K >> 5;

  // prologue: stage tiles 0 (slot 0) and 1 (slot 1)
  gload16(gA,               dA);
  gload16(gA + lda128,      dA + 4096);
  gload16(gB,               dB);
  gload16(gB + ldb128,      dB + 4096);
  gload16(gA + 32,          dA + 8192);
  gload16(gA + 32 + lda128, dA + 8192 + 4096);
  gload16(gB + 32,          dB + 8192);
  gload16(gB + 32 + ldb128, dB + 8192 + 4096);
  asm volatile("s_waitcnt vmcnt(4)" ::: "memory");   // tile 0 resident
  __builtin_amdgcn_s_barrier();
  __builtin_amdgcn_sched_barrier(0);

  for (int t = 0; t < nt; ++t) {
    const int s  = t % 3;
    const int ps = (t + 2) % 3;
    const bool pf = (t + 2) < nt;
    const f16* Ab = As + s * 8192 + aoff;
    const f16* Bb = Bs + s * 8192 + boff;
    const f16* gAt = gA + (size_t)(t + 2) * 32;
    const f16* gBt = gB + (size_t)(t + 2) * 32;

    // ---- phase 1: stage A(t+2) | read bf[0..3], af[0..3] | MFMA m0-3 ----
    if (pf) {
      gload16(gAt,          dA + ps * 8192);
      gload16(gAt + lda128, dA + ps * 8192 + 4096);
    }
    f16x8 bf[4], af[4];
#pragma unroll
    for (int n = 0; n < 4; ++n) bf[n] = *(const f16x8*)(Bb + n * 512);
#pragma unroll
    for (int m = 0; m < 4; ++m) af[m] = *(const f16x8*)(Ab + m * 512);
    __builtin_amdgcn_sched_barrier(0);
    __builtin_amdgcn_s_barrier();
    __builtin_amdgcn_sched_barrier(0);
    __builtin_amdgcn_s_setprio(1);
#pragma unroll
    for (int m = 0; m < 4; ++m)
#pragma unroll
      for (int n = 0; n < 4; ++n)
        acc[m][n] = mfma16(af[m], bf[n], acc[m][n]);
    __builtin_amdgcn_s_setprio(0);
    __builtin_amdgcn_s_barrier();
    __builtin_amdgcn_sched_barrier(0);

    // ---- phase 2: stage B(t+2) | read af[4..7] | MFMA m4-7 ----
    if (pf) {
      gload16(gBt,          dB + ps * 8192);
      gload16(gBt + ldb128, dB + ps * 8192 + 4096);
    }
#pragma unroll
    for (int m = 0; m < 4; ++m) af[m] = *(const f16x8*)(Ab + (m + 4) * 512);
    __builtin_amdgcn_sched_barrier(0);
    __builtin_amdgcn_s_barrier();
    __builtin_amdgcn_sched_barrier(0);
    __builtin_amdgcn_s_setprio(1);
#pragma unroll
    for (int m = 0; m < 4; ++m)
#pragma unroll
      for (int n = 0; n < 4; ++n)
        acc[m + 4][n] = mfma16(af[m], bf[n], acc[m + 4][n]);
    __builtin_amdgcn_s_setprio(0);
    if (pf) asm volatile("s_waitcnt vmcnt(4)" ::: "memory");  // t+1 resident
    else    asm volatile("s_waitcnt vmcnt(0)" ::: "memory");  // final drain
    __builtin_amdgcn_s_barrier();
    __builtin_amdgcn_sched_barrier(0);
  }

  // epilogue. C/D layout: col = lane&15, row = (lane>>4)*4 + j
  const int cr = (lane >> 4) * 4;
  const int cc = lane & 15;
  const int wrow = (w >> 2) * 128;
  const int wcol = (w & 3) * 64;

  if (MODE == 0) {
    f16* C = (f16*)Cp;
    float bv[4];
#pragma unroll
    for (int n = 0; n < 4; ++n) bv[n] = bias[c0 + wcol + n * 16 + cc];
#pragma unroll
    for (int m = 0; m < 8; ++m)
#pragma unroll
      for (int j = 0; j < 4; ++j) {
        const int r = r0 + wrow + m * 16 + cr + j;
#pragma unroll
        for (int n = 0; n < 4; ++n) {
          const int c = c0 + wcol + n * 16 + cc;
          C[(size_t)r * ldc + c] = (f16)(acc[m][n][j] + bv[n]);
        }
      }
  } else if (MODE == 1) {
    f16* C = (f16*)Cp;
#pragma unroll
    for (int m = 0; m < 8; ++m)
#pragma unroll
      for (int j = 0; j < 4; ++j) {
        const int r = r0 + wrow + m * 16 + cr + j;
        float rs = 0.0f;
#pragma unroll
        for (int n = 0; n < 4; ++n) {
          const int c = c0 + wcol + n * 16 + cc;
          float e = __expf(acc[m][n][j] * scale);
          rs += e;
          C[(size_t)r * ldc + c] = (f16)e;
        }
        rs += __shfl_xor(rs, 1);
        rs += __shfl_xor(rs, 2);
        rs += __shfl_xor(rs, 4);
        rs += __shfl_xor(rs, 8);
        if (cc == 0) unsafeAtomicAdd(&den[r], rs);
      }
  } else {
    float* C = (float*)Cp;
#pragma unroll
    for (int m = 0; m < 8; ++m)
#pragma unroll
      for (int j = 0; j < 4; ++j) {
        const int r = r0 + wrow + m * 16 + cr + j;
#pragma unroll
        for (int n = 0; n < 4; ++n) {
          const int c = c0 + wcol + n * 16 + cc;
          unsafeAtomicAdd(&C[(size_t)r * ldc + c], acc[m][n][j]);
        }
      }
  }
}

// ---------------------------------------------------------------------------
// 128x128 / BK=32 template (proven) -- used for q12 and FFN (small grids)
// ---------------------------------------------------------------------------
template<int MODE>
__global__ __launch_bounds__(256)
void gemm_bt(const f16* __restrict__ A, const f16* __restrict__ B,
             void* __restrict__ Cp, int K, int lda, int ldb, int ldc,
             const float* __restrict__ bias, float* __restrict__ den,
             float scale)
{
  __shared__ __align__(16) f16 As[128 * 32];
  __shared__ __align__(16) f16 Bs[128 * 32];
  const int t    = threadIdx.x;
  const int w    = t >> 6;
  const int lane = t & 63;
  const int r0   = blockIdx.y * 128;
  const int c0   = blockIdx.x * 128;
  const int koff = blockIdx.z * K;

  const int lr = lane >> 2;
  const int lc = (lane & 3) * 8;

  f32x4 acc[4][4];
#pragma unroll
  for (int m = 0; m < 4; ++m)
#pragma unroll
    for (int n = 0; n < 4; ++n)
      acc[m][n] = (f32x4)0.0f;

  const int wr = (w >> 1) * 64;
  const int wc = (w & 1) * 64;
  const int fr = lane & 15;
  const int fs = (lane >> 4) * 8;

  for (int k0 = 0; k0 < K; k0 += 32) {
#pragma unroll
    for (int i = 0; i < 2; ++i) {
      const int ch = i * 4 + w;
      gload16(A + (size_t)(r0 + ch * 16 + lr) * lda + (koff + k0 + lc),
              &As[ch * 512 + lane * 8]);
      gload16(B + (size_t)(c0 + ch * 16 + lr) * ldb + (koff + k0 + lc),
              &Bs[ch * 512 + lane * 8]);
    }
    __syncthreads();

    f16x8 af[4], bfv[4];
#pragma unroll
    for (int m = 0; m < 4; ++m)
      af[m] = *(const f16x8*)&As[(wr + m * 16 + fr) * 32 + fs];
#pragma unroll
    for (int n = 0; n < 4; ++n)
      bfv[n] = *(const f16x8*)&Bs[(wc + n * 16 + fr) * 32 + fs];
#pragma unroll
    for (int m = 0; m < 4; ++m)
#pragma unroll
      for (int n = 0; n < 4; ++n)
        acc[m][n] = mfma16(af[m], bfv[n], acc[m][n]);
    __syncthreads();
  }

  const int cr = (lane >> 4) * 4;
  const int cc = lane & 15;

  if (MODE == 0) {
    f16* C = (f16*)Cp;
#pragma unroll
    for (int m = 0; m < 4; ++m)
#pragma unroll
      for (int j = 0; j < 4; ++j) {
        const int r = r0 + wr + m * 16 + cr + j;
#pragma unroll
        for (int n = 0; n < 4; ++n) {
          const int c = c0 + wc + n * 16 + cc;
          C[(size_t)r * ldc + c] = (f16)(acc[m][n][j] + bias[c]);
        }
      }
  } else if (MODE == 2) {
    float* C = (float*)Cp;
#pragma unroll
    for (int m = 0; m < 4; ++m)
#pragma unroll
      for (int j = 0; j < 4; ++j) {
        const int r = r0 + wr + m * 16 + cr + j;
#pragma unroll
        for (int n = 0; n < 4; ++n) {
          const int c = c0 + wc + n * 16 + cc;
          unsafeAtomicAdd(&C[(size_t)r * ldc + c], acc[m][n][j]);
        }
      }
  } else {
    float* C = (float*)Cp;
#pragma unroll
    for (int m = 0; m < 4; ++m)
#pragma unroll
      for (int j = 0; j < 4; ++j) {
        const int r = r0 + wr + m * 16 + cr + j;
#pragma unroll
        for (int n = 0; n < 4; ++n) {
          const int c = c0 + wc + n * 16 + cc;
          C[(size_t)r * ldc + c] = acc[m][n][j] + bias[c];
        }
      }
  }
}

// f32 -> f16 vectorized convert (n4 = n/4)
__global__ __launch_bounds__(256)
void cvt_f16(const float* __restrict__ in, f16* __restrict__ out, int n4) {
  int i = blockIdx.x * 256 + threadIdx.x;
  const int stride = gridDim.x * 256;
  for (; i < n4; i += stride) {
    float4 v = ((const float4*)in)[i];
    f16x4 o = { (f16)v.x, (f16)v.y, (f16)v.z, (f16)v.w };
    ((f16x4*)out)[i] = o;
  }
}

__global__ __launch_bounds__(256)
void init_misc(const float* __restrict__ bc1, const float* __restrict__ bd1,
               const float* __restrict__ bc2, const float* __restrict__ bc3,
               const float* __restrict__ bd2, const float* __restrict__ bd3,
               float* __restrict__ biasq, float* __restrict__ biaskv,
               float* __restrict__ den)
{
  const int i = blockIdx.x * 256 + threadIdx.x;
  if (i < 1024) {
    biasq[i]         = bc1[i];
    biasq[1024 + i]  = bd1[i];
    biaskv[i]        = bc2[i];
    biaskv[1024 + i] = bc3[i];
    biaskv[2048 + i] = bd2[i];
    biaskv[3072 + i] = bd3[i];
  }
  den[i] = 0.0f;
}

__global__ __launch_bounds__(256)
void zero_f32(float4* __restrict__ p, int n4) {
  int i = blockIdx.x * 256 + threadIdx.x;
  const int stride = gridDim.x * 256;
  float4 z; z.x = 0.f; z.y = 0.f; z.z = 0.f; z.w = 0.f;
  for (; i < n4; i += stride) p[i] = z;
}

__global__ __launch_bounds__(256)
void fill_f32(float* __restrict__ p, float v, int n) {
  int i = blockIdx.x * 256 + threadIdx.x;
  const int stride = gridDim.x * 256;
  for (; i < n; i += stride) p[i] = v;
}

// vT[c][r] = kv[r][col_ofs + c]   (r<8192, c<1024), 64x64 LDS tiles
__global__ __launch_bounds__(256)
void transpose_v(const f16* __restrict__ kv, f16* __restrict__ vT, int col_ofs) {
  __shared__ f16 tile[64][66];
  const int r0 = blockIdx.x * 64;
  const int c0 = blockIdx.y * 64;
  const int tx = threadIdx.x;
  const int ty = threadIdx.y;
  for (int i = ty; i < 64; i += 4)
    tile[i][tx] = kv[(size_t)(r0 + i) * 4096 + col_ofs + c0 + tx];
  __syncthreads();
  for (int i = ty; i < 64; i += 4)
    vT[(size_t)(c0 + i) * NBANK + r0 + tx] = tile[tx][i];
}

// cpair = (f1/den1)*(f2/den2); LayerNorm over 1024; PReLU; -> x f16
__global__ __launch_bounds__(256)
void gate_ln(const float* __restrict__ f1, const float* __restrict__ f2,
             const float* __restrict__ den,
             const float* __restrict__ lnw, const float* __restrict__ lnb,
             const float* __restrict__ pa, f16* __restrict__ x)
{
  const int row = blockIdx.x;
  const int t   = threadIdx.x;
  const int lane = t & 63, w = t >> 6;
  const float inv1 = 1.0f / den[row];
  const float inv2 = 1.0f / den[NROIS + row];
  const float4 a = ((const float4*)(f1 + (size_t)row * LAT))[t];
  const float4 b = ((const float4*)(f2 + (size_t)row * LAT))[t];
  float c[4] = { a.x * b.x * inv1 * inv2, a.y * b.y * inv1 * inv2,
                 a.z * b.z * inv1 * inv2, a.w * b.w * inv1 * inv2 };
  float s = c[0] + c[1] + c[2] + c[3];
  float q = c[0]*c[0] + c[1]*c[1] + c[2]*c[2] + c[3]*c[3];
#pragma unroll
  for (int m = 1; m < 64; m <<= 1) {
    s += __shfl_xor(s, m);
    q += __shfl_xor(q, m);
  }
  __shared__ float red[8];
  if (lane == 0) { red[w] = s; red[4 + w] = q; }
  __syncthreads();
  s = red[0] + red[1] + red[2] + red[3];
  q = red[4] + red[5] + red[6] + red[7];
  const float mu  = s * (1.0f / LAT);
  const float var = q * (1.0f / LAT) - mu * mu;
  const float rs  = rsqrtf(var + 1e-5f);
  const float slope = pa[0];
  f16x4 o;
#pragma unroll
  for (int j = 0; j < 4; ++j) {
    float xv = (c[j] - mu) * rs * lnw[t * 4 + j] + lnb[t * 4 + j];
    xv = (xv >= 0.0f) ? xv : slope * xv;
    o[j] = (f16)xv;
  }
  ((f16x4*)(x + (size_t)row * LAT))[t] = o;
}

extern "C" void kernel_launch(void* const* d_in, const int* in_sizes, int n_in,
                              void* d_out, int out_size, void* d_ws, size_t ws_size,
                              hipStream_t stream) {
  const float* feat = (const float*)d_in[0];
  const float* bank = (const float*)d_in[1];
  const float* Wc1  = (const float*)d_in[2];
  const float* bc1  = (const float*)d_in[3];
  const float* Wc2  = (const float*)d_in[4];
  const float* bc2  = (const float*)d_in[5];
  const float* Wc3  = (const float*)d_in[6];
  const float* bc3  = (const float*)d_in[7];
  const float* Wd1  = (const float*)d_in[8];
  const float* bd1  = (const float*)d_in[9];
  const float* Wd2  = (const float*)d_in[10];
  const float* bd2  = (const float*)d_in[11];
  const float* Wd3  = (const float*)d_in[12];
  const float* bd3  = (const float*)d_in[13];
  const float* lnw  = (const float*)d_in[14];
  const float* lnb  = (const float*)d_in[15];
  const float* pa   = (const float*)d_in[16];
  const float* Wffn = (const float*)d_in[17];
  const float* bffn = (const float*)d_in[18];

  const size_t MBy = 1ull << 20;

  if (ws_size < 133 * MBy) {
    fill_f32<<<dim3(2048), dim3(256), 0, stream>>>((float*)d_out, 12345.0f, out_size);
    return;
  }

  // allow 96KB dynamic LDS for the 256^2 template (host-side, capture-safe)
  const int DYN_LDS = 3 * 2 * 8192 * 2;  // 98304
  (void)hipFuncSetAttribute(reinterpret_cast<const void*>(&gemm2<0>),
                            hipFuncAttributeMaxDynamicSharedMemorySize, DYN_LDS);
  (void)hipFuncSetAttribute(reinterpret_cast<const void*>(&gemm2<1>),
                            hipFuncAttributeMaxDynamicSharedMemorySize, DYN_LDS);
  (void)hipFuncSetAttribute(reinterpret_cast<const void*>(&gemm2<2>),
                            hipFuncAttributeMaxDynamicSharedMemorySize, DYN_LDS);

  char* ws = (char*)d_ws;
  f16*   kvb  = (f16*)(ws);              // [0,64M)   kv = k1|v1|k2|v2
  f16*   q12  = (f16*)(ws + 64 * MBy);   // [64,80M)  q1|q2
  f16*   Wfb  = (f16*)(ws + 80 * MBy);   // [80,84M)  Wffn f16
  f16*   WQ   = (f16*)(ws + 84 * MBy);   // [84,92M)  phase1 only
  f16*   xbuf = (f16*)(ws + 84 * MBy);   // [84,92M)  after vT dead
  f16*   vTb  = (f16*)(ws + 84 * MBy);   // [84,100M) per-branch
  f16*   BB   = (f16*)(ws + 92 * MBy);   // [92,124M) bank f16, phase1 only
  f16*   Eb   = (f16*)(ws + 100 * MBy);  // [100,132M) E chunk [2048x8192]
  float* biasq  = (float*)(ws + 132 * MBy);
  float* biaskv = (float*)(ws + 132 * MBy + 8192);
  float* den    = (float*)(ws + 132 * MBy + 24576);
  f16*   WKV = (f16*)d_out;                       // [0,16M)  phase1
  f16*   FB  = (f16*)((char*)d_out + 16 * MBy);   // [16,32M) phase1
  float* f1  = (float*)d_out;                     // [0,16M)  phase3
  float* f2  = (float*)((char*)d_out + 16 * MBy); // [16,32M) phase3

  init_misc<<<dim3(32), dim3(256), 0, stream>>>(bc1, bd1, bc2, bc3, bd2, bd3,
                                                biasq, biaskv, den);

  auto cvt = [&](const float* in, f16* out, size_t n) {
    int n4 = (int)(n / 4);
    int blocks = (n4 + 255) / 256;
    if (blocks > 2048) blocks = 2048;
    cvt_f16<<<dim3(blocks), dim3(256), 0, stream>>>(in, out, n4);
  };
  cvt(Wc1, WQ,                          (size_t)1024 * 2048);
  cvt(Wd1, WQ + (size_t)1024 * 2048,    (size_t)1024 * 2048);
  cvt(feat, FB, (size_t)NROIS * DIMIN);
  cvt(Wc2, WKV,                         (size_t)1024 * 2048);
  cvt(Wc3, WKV + (size_t)1024 * 2048,   (size_t)1024 * 2048);
  cvt(Wd2, WKV + (size_t)2048 * 2048,   (size_t)1024 * 2048);
  cvt(Wd3, WKV + (size_t)3072 * 2048,   (size_t)1024 * 2048);
  cvt(bank, BB, (size_t)NBANK * DIMIN);
  cvt(Wffn, Wfb, (size_t)2048 * 1024);

  // q12 = FB @ WQ^T + biasq   [4096,2048]  (128^2 template, 512 blocks)
  gemm_bt<0><<<dim3(16, 32, 1), 256, 0, stream>>>(
      FB, WQ, q12, 2048, 2048, 2048, 2048, biasq, nullptr, 0.0f);
  // kv = BB @ WKV^T + biaskv  [8192,4096]  (256^2 template, 512 blocks)
  gemm2<0><<<dim3(16, 32, 1), 512, DYN_LDS, stream>>>(
      BB, WKV, kvb, 2048, 2048, 2048, 4096, biaskv, nullptr, 0.0f);

  // zero f1,f2 (all of d_out) -- FB/WKV dead now
  zero_f32<<<dim3(2048), dim3(256), 0, stream>>>((float4*)d_out, (32 * (int)MBy) / 16);

  const float scl = 0.03125f;  // 1/sqrt(1024)
  for (int b = 0; b < 2; ++b) {
    transpose_v<<<dim3(128, 16, 1), dim3(64, 4), 0, stream>>>(
        kvb, vTb, 1024 + b * 2048);
    float* fb = b ? f2 : f1;
    for (int chunk = 0; chunk < 2; ++chunk) {
      // E = exp(q_b[chunk] @ k_b^T / 32)  [2048,8192] + row sums (256 blocks)
      gemm2<1><<<dim3(32, 8, 1), 512, DYN_LDS, stream>>>(
          q12 + (size_t)chunk * 2048 * 2048 + b * 1024, kvb + b * 2048,
          Eb, 1024, 2048, 4096, 8192,
          nullptr, den + b * NROIS + chunk * 2048, scl);
      // f_b[chunk] += E @ vT^T  (split-K=8, f32 atomics, 256 blocks)
      gemm2<2><<<dim3(4, 8, 8), 512, DYN_LDS, stream>>>(
          Eb, vTb, fb + (size_t)chunk * 2048 * 1024, 1024, 8192, 8192, 1024,
          nullptr, nullptr, 0.0f);
    }
  }

  gate_ln<<<dim3(NROIS), dim3(256), 0, stream>>>(f1, f2, den, lnw, lnb, pa, xbuf);

  // out = x @ Wffn^T + bffn  [4096,2048] f32 (128^2 template)
  gemm_bt<3><<<dim3(16, 32, 1), 256, 0, stream>>>(
      xbuf, Wfb, (float*)d_out, 1024, 1024, 1024, 2048, bffn, nullptr, 0.0f);
}

// Round 4
// 932.110 us; speedup vs baseline: 1.2367x; 1.1829x over previous
//
#include <hip/hip_runtime.h>
#include <cstdint>

typedef _Float16 f16;
typedef __attribute__((ext_vector_type(8))) _Float16 f16x8;
typedef __attribute__((ext_vector_type(4))) _Float16 f16x4;
typedef __attribute__((ext_vector_type(4))) float f32x4;

#define NROIS 4096
#define NBANK 8192
#define DIMIN 2048
#define LAT   1024

__device__ __forceinline__ void gload16(const f16* g, f16* l) {
  __builtin_amdgcn_global_load_lds(
      (const __attribute__((address_space(1))) void*)g,
      (__attribute__((address_space(3))) void*)l, 16, 0, 0);
}

__device__ __forceinline__ f32x4 mfma16(f16x8 a, f16x8 b, f32x4 c) {
  return __builtin_amdgcn_mfma_f32_16x16x32_f16(a, b, c, 0, 0, 0);
}

// ---------------------------------------------------------------------------
// 256x256 tile, BK=32, 512 threads (8 waves 2Mx4N). v2:
//  - 4-slot LDS rotation (128KB): ONE barrier + ONE counted vmcnt per K-tile.
//    Safety: 1 barrier/iter bounds wave skew to +-1 iter; concurrent reads
//    touch slots {t,t+1}%4, staging targets {t+2,t+3}%4 -> disjoint.
//    vmcnt(4) at end of iter t completes tile t+1's 4 loads (per-wave), and
//    the barrier publishes all waves' staging before anyone reads.
//  - T2 XOR swizzle: LDS[R][chunk] holds G[R][chunk ^ ((R>>1)&3)] (16B chunks)
//    -> each 16-lane frag-read subgroup spreads over all 8 bank groups.
//    global_load_lds keeps a LINEAR dest; the swizzle is applied on the
//    global SOURCE address and again (involution) on the LDS read offset.
// MODE 0: C f16 = acc + bias[col]
// MODE 1: C f16 = exp(acc*scale); den[row] += row-sum (atomic)
// MODE 2: C f32 atomicAdd(acc)  (split-K via blockIdx.z)
// MODE 4: paired-branch PV: z = branch*4 + split; batch strides hardcoded.
// ---------------------------------------------------------------------------
#define A_BSTR ((size_t)2048 * 8192)   // E1 = E0 + 32MB
#define B_BSTR ((size_t)1024 * 8192)   // vT1 = vT0 + 16MB
#define C_BSTR ((size_t)4194304)       // f2 = f1 + 16MB

template<int MODE>
__global__ __launch_bounds__(512, 1)
void gemm2(const f16* __restrict__ A, const f16* __restrict__ B,
           void* __restrict__ Cp, int K, int lda, int ldb, int ldc,
           const float* __restrict__ bias, float* __restrict__ den,
           float scale)
{
  extern __shared__ __align__(16) f16 lds[];   // [4][8192] A | [4][8192] B
  f16* As = lds;
  f16* Bs = lds + 4 * 8192;

  const int tid  = threadIdx.x;
  const int w    = tid >> 6;
  const int lane = tid & 63;

  int br = 0, sp = blockIdx.z;
  if (MODE == 4) { br = blockIdx.z >> 2; sp = blockIdx.z & 3; }
  const f16* Abase_g = A;
  const f16* Bbase_g = B;
  if (MODE == 4) { Abase_g += (size_t)br * A_BSTR; Bbase_g += (size_t)br * B_BSTR; }

  // XCD swizzle (bijective: gx*gy % 8 == 0 for all our launches)
  const int gx = gridDim.x;
  const int nwg = gx * gridDim.y;
  int id = blockIdx.y * gx + blockIdx.x;
  id = (id & 7) * (nwg >> 3) + (id >> 3);
  const int bx = id % gx, by = id / gx;

  const int r0   = by * 256;
  const int c0   = bx * 256;
  const int koff = sp * K;

  // staging: dest = LDS row (tid>>2), chunk (tid&3); source chunk swizzled
  const int rr = tid >> 2;
  const int ci = (tid & 3) ^ ((tid >> 3) & 3);
  const f16* gA = Abase_g + (size_t)(r0 + rr) * lda + koff + ci * 8;
  const f16* gB = Bbase_g + (size_t)(c0 + rr) * ldb + koff + ci * 8;
  const size_t lda128 = (size_t)128 * lda;
  const size_t ldb128 = (size_t)128 * ldb;
  f16* dA = As + tid * 8;
  f16* dB = Bs + tid * 8;

  // fragment read offsets (swizzled k-chunk; (row+16k)&7 == row&7 so the XOR
  // term depends only on lane)
  const int swz  = ((lane >> 4) ^ ((lane >> 1) & 3)) * 8;
  const int aoff = ((w >> 2) * 128 + (lane & 15)) * 32 + swz;
  const int boff = ((w & 3) * 64 + (lane & 15)) * 32 + swz;

  f32x4 acc[8][4];
#pragma unroll
  for (int m = 0; m < 8; ++m)
#pragma unroll
    for (int n = 0; n < 4; ++n)
      acc[m][n] = (f32x4)0.0f;

  const int nt = K >> 5;

  // prologue: stage tiles 0 (slot 0) and 1 (slot 1)
  gload16(gA,               dA);
  gload16(gA + lda128,      dA + 4096);
  gload16(gB,               dB);
  gload16(gB + ldb128,      dB + 4096);
  gload16(gA + 32,          dA + 8192);
  gload16(gA + 32 + lda128, dA + 8192 + 4096);
  gload16(gB + 32,          dB + 8192);
  gload16(gB + 32 + ldb128, dB + 8192 + 4096);
  asm volatile("s_waitcnt vmcnt(4)" ::: "memory");   // tile 0 resident
  __builtin_amdgcn_s_barrier();
  __builtin_amdgcn_sched_barrier(0);

  for (int t = 0; t < nt; ++t) {
    const int s = (t & 3) * 8192;
    const f16* Ab = As + s + aoff;
    const f16* Bb = Bs + s + boff;
    const bool pf = (t + 2) < nt;
    if (pf) {
      const int ps = ((t + 2) & 3) * 8192;
      const f16* gAt = gA + (size_t)(t + 2) * 32;
      const f16* gBt = gB + (size_t)(t + 2) * 32;
      gload16(gAt,          dA + ps);
      gload16(gAt + lda128, dA + ps + 4096);
      gload16(gBt,          dB + ps);
      gload16(gBt + ldb128, dB + ps + 4096);
    }
    f16x8 af[8], bf[4];
#pragma unroll
    for (int n = 0; n < 4; ++n) bf[n] = *(const f16x8*)(Bb + n * 512);
#pragma unroll
    for (int m = 0; m < 8; ++m) af[m] = *(const f16x8*)(Ab + m * 512);
    __builtin_amdgcn_s_setprio(1);
#pragma unroll
    for (int m = 0; m < 8; ++m)
#pragma unroll
      for (int n = 0; n < 4; ++n)
        acc[m][n] = mfma16(af[m], bf[n], acc[m][n]);
    __builtin_amdgcn_s_setprio(0);
    __builtin_amdgcn_sched_barrier(0);
    if (pf) asm volatile("s_waitcnt vmcnt(4)" ::: "memory");  // t+1 resident
    else    asm volatile("s_waitcnt vmcnt(0)" ::: "memory");
    __builtin_amdgcn_s_barrier();
    __builtin_amdgcn_sched_barrier(0);
  }

  // epilogue. C/D layout: col = lane&15, row = (lane>>4)*4 + j
  const int cr = (lane >> 4) * 4;
  const int cc = lane & 15;
  const int wrow = (w >> 2) * 128;
  const int wcol = (w & 3) * 64;

  if (MODE == 0) {
    f16* C = (f16*)Cp;
    float bv[4];
#pragma unroll
    for (int n = 0; n < 4; ++n) bv[n] = bias[c0 + wcol + n * 16 + cc];
#pragma unroll
    for (int m = 0; m < 8; ++m)
#pragma unroll
      for (int j = 0; j < 4; ++j) {
        const int r = r0 + wrow + m * 16 + cr + j;
#pragma unroll
        for (int n = 0; n < 4; ++n) {
          const int c = c0 + wcol + n * 16 + cc;
          C[(size_t)r * ldc + c] = (f16)(acc[m][n][j] + bv[n]);
        }
      }
  } else if (MODE == 1) {
    f16* C = (f16*)Cp;
#pragma unroll
    for (int m = 0; m < 8; ++m)
#pragma unroll
      for (int j = 0; j < 4; ++j) {
        const int r = r0 + wrow + m * 16 + cr + j;
        float rs = 0.0f;
#pragma unroll
        for (int n = 0; n < 4; ++n) {
          const int c = c0 + wcol + n * 16 + cc;
          float e = __expf(acc[m][n][j] * scale);
          rs += e;
          C[(size_t)r * ldc + c] = (f16)e;
        }
        rs += __shfl_xor(rs, 1);
        rs += __shfl_xor(rs, 2);
        rs += __shfl_xor(rs, 4);
        rs += __shfl_xor(rs, 8);
        if (cc == 0) unsafeAtomicAdd(&den[r], rs);
      }
  } else {  // MODE 2 / MODE 4: f32 atomic accumulate
    float* C = (float*)Cp;
    if (MODE == 4) C += (size_t)br * C_BSTR;
#pragma unroll
    for (int m = 0; m < 8; ++m)
#pragma unroll
      for (int j = 0; j < 4; ++j) {
        const int r = r0 + wrow + m * 16 + cr + j;
#pragma unroll
        for (int n = 0; n < 4; ++n) {
          const int c = c0 + wcol + n * 16 + cc;
          unsafeAtomicAdd(&C[(size_t)r * ldc + c], acc[m][n][j]);
        }
      }
  }
}

// ---------------------------------------------------------------------------
// 128x128 / BK=32 template + T2 swizzle -- used for q12 and FFN
// ---------------------------------------------------------------------------
template<int MODE>
__global__ __launch_bounds__(256)
void gemm_bt(const f16* __restrict__ A, const f16* __restrict__ B,
             void* __restrict__ Cp, int K, int lda, int ldb, int ldc,
             const float* __restrict__ bias, float* __restrict__ den,
             float scale)
{
  __shared__ __align__(16) f16 As[128 * 32];
  __shared__ __align__(16) f16 Bs[128 * 32];
  const int t    = threadIdx.x;
  const int w    = t >> 6;
  const int lane = t & 63;
  const int r0   = blockIdx.y * 128;
  const int c0   = blockIdx.x * 128;
  const int koff = blockIdx.z * K;

  const int lr = lane >> 2;                            // row within 16-row chunk
  const int lc = ((lane & 3) ^ ((lane >> 3) & 3)) * 8; // swizzled source chunk

  f32x4 acc[4][4];
#pragma unroll
  for (int m = 0; m < 4; ++m)
#pragma unroll
    for (int n = 0; n < 4; ++n)
      acc[m][n] = (f32x4)0.0f;

  const int wr = (w >> 1) * 64;
  const int wc = (w & 1) * 64;
  const int fr = lane & 15;
  const int fs = ((lane >> 4) ^ ((lane >> 1) & 3)) * 8; // swizzled read chunk

  for (int k0 = 0; k0 < K; k0 += 32) {
#pragma unroll
    for (int i = 0; i < 2; ++i) {
      const int ch = i * 4 + w;
      gload16(A + (size_t)(r0 + ch * 16 + lr) * lda + (koff + k0 + lc),
              &As[ch * 512 + lane * 8]);
      gload16(B + (size_t)(c0 + ch * 16 + lr) * ldb + (koff + k0 + lc),
              &Bs[ch * 512 + lane * 8]);
    }
    __syncthreads();

    f16x8 af[4], bfv[4];
#pragma unroll
    for (int m = 0; m < 4; ++m)
      af[m] = *(const f16x8*)&As[(wr + m * 16 + fr) * 32 + fs];
#pragma unroll
    for (int n = 0; n < 4; ++n)
      bfv[n] = *(const f16x8*)&Bs[(wc + n * 16 + fr) * 32 + fs];
#pragma unroll
    for (int m = 0; m < 4; ++m)
#pragma unroll
      for (int n = 0; n < 4; ++n)
        acc[m][n] = mfma16(af[m], bfv[n], acc[m][n]);
    __syncthreads();
  }

  const int cr = (lane >> 4) * 4;
  const int cc = lane & 15;

  if (MODE == 0) {
    f16* C = (f16*)Cp;
#pragma unroll
    for (int m = 0; m < 4; ++m)
#pragma unroll
      for (int j = 0; j < 4; ++j) {
        const int r = r0 + wr + m * 16 + cr + j;
#pragma unroll
        for (int n = 0; n < 4; ++n) {
          const int c = c0 + wc + n * 16 + cc;
          C[(size_t)r * ldc + c] = (f16)(acc[m][n][j] + bias[c]);
        }
      }
  } else {
    float* C = (float*)Cp;
#pragma unroll
    for (int m = 0; m < 4; ++m)
#pragma unroll
      for (int j = 0; j < 4; ++j) {
        const int r = r0 + wr + m * 16 + cr + j;
#pragma unroll
        for (int n = 0; n < 4; ++n) {
          const int c = c0 + wc + n * 16 + cc;
          C[(size_t)r * ldc + c] = acc[m][n][j] + bias[c];
        }
      }
  }
}

// f32 -> f16 vectorized convert (n4 = n/4)
__global__ __launch_bounds__(256)
void cvt_f16(const float* __restrict__ in, f16* __restrict__ out, int n4) {
  int i = blockIdx.x * 256 + threadIdx.x;
  const int stride = gridDim.x * 256;
  for (; i < n4; i += stride) {
    float4 v = ((const float4*)in)[i];
    f16x4 o = { (f16)v.x, (f16)v.y, (f16)v.z, (f16)v.w };
    ((f16x4*)out)[i] = o;
  }
}

__global__ __launch_bounds__(256)
void init_misc(const float* __restrict__ bc1, const float* __restrict__ bd1,
               const float* __restrict__ bc2, const float* __restrict__ bc3,
               const float* __restrict__ bd2, const float* __restrict__ bd3,
               float* __restrict__ biasq, float* __restrict__ biaskv,
               float* __restrict__ den)
{
  const int i = blockIdx.x * 256 + threadIdx.x;
  if (i < 1024) {
    biasq[i]         = bc1[i];
    biasq[1024 + i]  = bd1[i];
    biaskv[i]        = bc2[i];
    biaskv[1024 + i] = bc3[i];
    biaskv[2048 + i] = bd2[i];
    biaskv[3072 + i] = bd3[i];
  }
  den[i] = 0.0f;
}

__global__ __launch_bounds__(256)
void zero_f32(float4* __restrict__ p, int n4) {
  int i = blockIdx.x * 256 + threadIdx.x;
  const int stride = gridDim.x * 256;
  float4 z; z.x = 0.f; z.y = 0.f; z.z = 0.f; z.w = 0.f;
  for (; i < n4; i += stride) p[i] = z;
}

__global__ __launch_bounds__(256)
void fill_f32(float* __restrict__ p, float v, int n) {
  int i = blockIdx.x * 256 + threadIdx.x;
  const int stride = gridDim.x * 256;
  for (; i < n; i += stride) p[i] = v;
}

// vT[c][r] = kv[r][col_ofs + c]   (r<8192, c<1024), 64x64 LDS tiles
__global__ __launch_bounds__(256)
void transpose_v(const f16* __restrict__ kv, f16* __restrict__ vT, int col_ofs) {
  __shared__ f16 tile[64][66];
  const int r0 = blockIdx.x * 64;
  const int c0 = blockIdx.y * 64;
  const int tx = threadIdx.x;
  const int ty = threadIdx.y;
  for (int i = ty; i < 64; i += 4)
    tile[i][tx] = kv[(size_t)(r0 + i) * 4096 + col_ofs + c0 + tx];
  __syncthreads();
  for (int i = ty; i < 64; i += 4)
    vT[(size_t)(c0 + i) * NBANK + r0 + tx] = tile[tx][i];
}

// cpair = (f1/den1)*(f2/den2); LayerNorm over 1024; PReLU; -> x f16
__global__ __launch_bounds__(256)
void gate_ln(const float* __restrict__ f1, const float* __restrict__ f2,
             const float* __restrict__ den,
             const float* __restrict__ lnw, const float* __restrict__ lnb,
             const float* __restrict__ pa, f16* __restrict__ x)
{
  const int row = blockIdx.x;
  const int t   = threadIdx.x;
  const int lane = t & 63, w = t >> 6;
  const float inv1 = 1.0f / den[row];
  const float inv2 = 1.0f / den[NROIS + row];
  const float4 a = ((const float4*)(f1 + (size_t)row * LAT))[t];
  const float4 b = ((const float4*)(f2 + (size_t)row * LAT))[t];
  float c[4] = { a.x * b.x * inv1 * inv2, a.y * b.y * inv1 * inv2,
                 a.z * b.z * inv1 * inv2, a.w * b.w * inv1 * inv2 };
  float s = c[0] + c[1] + c[2] + c[3];
  float q = c[0]*c[0] + c[1]*c[1] + c[2]*c[2] + c[3]*c[3];
#pragma unroll
  for (int m = 1; m < 64; m <<= 1) {
    s += __shfl_xor(s, m);
    q += __shfl_xor(q, m);
  }
  __shared__ float red[8];
  if (lane == 0) { red[w] = s; red[4 + w] = q; }
  __syncthreads();
  s = red[0] + red[1] + red[2] + red[3];
  q = red[4] + red[5] + red[6] + red[7];
  const float mu  = s * (1.0f / LAT);
  const float var = q * (1.0f / LAT) - mu * mu;
  const float rs  = rsqrtf(var + 1e-5f);
  const float slope = pa[0];
  f16x4 o;
#pragma unroll
  for (int j = 0; j < 4; ++j) {
    float xv = (c[j] - mu) * rs * lnw[t * 4 + j] + lnb[t * 4 + j];
    xv = (xv >= 0.0f) ? xv : slope * xv;
    o[j] = (f16)xv;
  }
  ((f16x4*)(x + (size_t)row * LAT))[t] = o;
}

extern "C" void kernel_launch(void* const* d_in, const int* in_sizes, int n_in,
                              void* d_out, int out_size, void* d_ws, size_t ws_size,
                              hipStream_t stream) {
  const float* feat = (const float*)d_in[0];
  const float* bank = (const float*)d_in[1];
  const float* Wc1  = (const float*)d_in[2];
  const float* bc1  = (const float*)d_in[3];
  const float* Wc2  = (const float*)d_in[4];
  const float* bc2  = (const float*)d_in[5];
  const float* Wc3  = (const float*)d_in[6];
  const float* bc3  = (const float*)d_in[7];
  const float* Wd1  = (const float*)d_in[8];
  const float* bd1  = (const float*)d_in[9];
  const float* Wd2  = (const float*)d_in[10];
  const float* bd2  = (const float*)d_in[11];
  const float* Wd3  = (const float*)d_in[12];
  const float* bd3  = (const float*)d_in[13];
  const float* lnw  = (const float*)d_in[14];
  const float* lnb  = (const float*)d_in[15];
  const float* pa   = (const float*)d_in[16];
  const float* Wffn = (const float*)d_in[17];
  const float* bffn = (const float*)d_in[18];

  const size_t MBy = 1ull << 20;

  if (ws_size < 133 * MBy) {
    fill_f32<<<dim3(2048), dim3(256), 0, stream>>>((float*)d_out, 12345.0f, out_size);
    return;
  }
  const bool big = ws_size >= 181 * MBy;

  const int DYN_LDS = 4 * 2 * 8192 * 2;  // 131072 (128 KB)
  (void)hipFuncSetAttribute(reinterpret_cast<const void*>(&gemm2<0>),
                            hipFuncAttributeMaxDynamicSharedMemorySize, DYN_LDS);
  (void)hipFuncSetAttribute(reinterpret_cast<const void*>(&gemm2<1>),
                            hipFuncAttributeMaxDynamicSharedMemorySize, DYN_LDS);
  (void)hipFuncSetAttribute(reinterpret_cast<const void*>(&gemm2<2>),
                            hipFuncAttributeMaxDynamicSharedMemorySize, DYN_LDS);
  (void)hipFuncSetAttribute(reinterpret_cast<const void*>(&gemm2<4>),
                            hipFuncAttributeMaxDynamicSharedMemorySize, DYN_LDS);

  char* ws = (char*)d_ws;
  // persistent
  f16* kvb = (f16*)(ws);              // [0,64M)   kv = k1|v1|k2|v2
  f16* q12 = (f16*)(ws + 64 * MBy);   // [64,80M)  q1|q2
  f16* Wfb = (f16*)(ws + 80 * MBy);   // [80,84M)  Wffn f16
  f16* WQ  = (f16*)(ws + 84 * MBy);   // phase1 only
  f16* xbuf = (f16*)(ws + 84 * MBy);  // phase4 (after attention)
  // d_out doubles as scratch until the final GEMM overwrites it:
  f16*   WKV = (f16*)d_out;                       // [0,16M)  phase1
  f16*   FB  = (f16*)((char*)d_out + 16 * MBy);   // [16,32M) phase1
  float* f1  = (float*)d_out;                     // [0,16M)  phase3
  float* f2  = (float*)((char*)d_out + 16 * MBy); // [16,32M) phase3

  // path-dependent
  f16 *vT0, *vT1 = nullptr, *E0, *E1 = nullptr, *BB;
  float *biasq, *biaskv, *den;
  if (big) {
    vT0 = (f16*)(ws + 84 * MBy);    // [84,100M)
    vT1 = (f16*)(ws + 100 * MBy);   // [100,116M)
    E0  = (f16*)(ws + 116 * MBy);   // [116,148M)
    E1  = (f16*)(ws + 148 * MBy);   // [148,180M)
    BB  = (f16*)(ws + 116 * MBy);   // phase1 (dead before E0 written)
    biasq  = (float*)(ws + 180 * MBy);
    biaskv = (float*)(ws + 180 * MBy + 8192);
    den    = (float*)(ws + 180 * MBy + 24576);
  } else {
    vT0 = (f16*)(ws + 84 * MBy);    // [84,100M) per-branch reuse
    E0  = (f16*)(ws + 100 * MBy);   // [100,132M)
    BB  = (f16*)(ws + 92 * MBy);    // [92,124M) phase1
    biasq  = (float*)(ws + 132 * MBy);
    biaskv = (float*)(ws + 132 * MBy + 8192);
    den    = (float*)(ws + 132 * MBy + 24576);
  }

  init_misc<<<dim3(32), dim3(256), 0, stream>>>(bc1, bd1, bc2, bc3, bd2, bd3,
                                                biasq, biaskv, den);

  auto cvt = [&](const float* in, f16* out, size_t n) {
    int n4 = (int)(n / 4);
    int blocks = (n4 + 255) / 256;
    if (blocks > 2048) blocks = 2048;
    cvt_f16<<<dim3(blocks), dim3(256), 0, stream>>>(in, out, n4);
  };
  cvt(Wc1, WQ,                          (size_t)1024 * 2048);
  cvt(Wd1, WQ + (size_t)1024 * 2048,    (size_t)1024 * 2048);
  cvt(feat, FB, (size_t)NROIS * DIMIN);
  cvt(Wc2, WKV,                         (size_t)1024 * 2048);
  cvt(Wc3, WKV + (size_t)1024 * 2048,   (size_t)1024 * 2048);
  cvt(Wd2, WKV + (size_t)2048 * 2048,   (size_t)1024 * 2048);
  cvt(Wd3, WKV + (size_t)3072 * 2048,   (size_t)1024 * 2048);
  cvt(bank, BB, (size_t)NBANK * DIMIN);
  cvt(Wffn, Wfb, (size_t)2048 * 1024);

  // q12 = FB @ WQ^T + biasq   [4096,2048]  (128^2 template; WQ dead after)
  gemm_bt<0><<<dim3(16, 32, 1), 256, 0, stream>>>(
      FB, WQ, q12, 2048, 2048, 2048, 2048, biasq, nullptr, 0.0f);
  // kv = BB @ WKV^T + biaskv  [8192,4096]  (256^2 v2; BB/WKV dead after)
  gemm2<0><<<dim3(16, 32, 1), 512, DYN_LDS, stream>>>(
      BB, WKV, kvb, 2048, 2048, 2048, 4096, biaskv, nullptr, 0.0f);

  // zero f1,f2 (all of d_out)
  zero_f32<<<dim3(2048), dim3(256), 0, stream>>>((float4*)d_out, (32 * (int)MBy) / 16);

  const float scl = 0.03125f;  // 1/sqrt(1024)
  if (big) {
    transpose_v<<<dim3(128, 16, 1), dim3(64, 4), 0, stream>>>(kvb, vT0, 1024);
    transpose_v<<<dim3(128, 16, 1), dim3(64, 4), 0, stream>>>(kvb, vT1, 3072);
    for (int chunk = 0; chunk < 2; ++chunk) {
      const size_t qo = (size_t)chunk * 2048 * 2048;
      // E_b = exp(q_b[chunk] @ k_b^T / 32)  [2048,8192] + row sums
      gemm2<1><<<dim3(32, 8, 1), 512, DYN_LDS, stream>>>(
          q12 + qo, kvb, E0, 1024, 2048, 4096, 8192,
          nullptr, den + chunk * 2048, scl);
      gemm2<1><<<dim3(32, 8, 1), 512, DYN_LDS, stream>>>(
          q12 + qo + 1024, kvb + 2048, E1, 1024, 2048, 4096, 8192,
          nullptr, den + NROIS + chunk * 2048, scl);
      // f1[chunk] += E0 @ vT0^T ; f2[chunk] += E1 @ vT1^T  (batched, split-4)
      gemm2<4><<<dim3(4, 8, 8), 512, DYN_LDS, stream>>>(
          E0, vT0, f1 + (size_t)chunk * 2048 * 1024, 2048, 8192, 8192, 1024,
          nullptr, nullptr, 0.0f);
    }
  } else {
    for (int b = 0; b < 2; ++b) {
      transpose_v<<<dim3(128, 16, 1), dim3(64, 4), 0, stream>>>(
          kvb, vT0, 1024 + b * 2048);
      float* fb = b ? f2 : f1;
      for (int chunk = 0; chunk < 2; ++chunk) {
        gemm2<1><<<dim3(32, 8, 1), 512, DYN_LDS, stream>>>(
            q12 + (size_t)chunk * 2048 * 2048 + b * 1024, kvb + b * 2048,
            E0, 1024, 2048, 4096, 8192,
            nullptr, den + b * NROIS + chunk * 2048, scl);
        gemm2<2><<<dim3(4, 8, 4), 512, DYN_LDS, stream>>>(
            E0, vT0, fb + (size_t)chunk * 2048 * 1024, 2048, 8192, 8192, 1024,
            nullptr, nullptr, 0.0f);
      }
    }
  }

  // gate + LayerNorm + PReLU -> x f16 [4096,1024]  (vT regions dead)
  gate_ln<<<dim3(NROIS), dim3(256), 0, stream>>>(f1, f2, den, lnw, lnb, pa, xbuf);

  // out = x @ Wffn^T + bffn  [4096,2048] f32 (overwrites all of d_out)
  gemm_bt<3><<<dim3(16, 32, 1), 256, 0, stream>>>(
      xbuf, Wfb, (float*)d_out, 1024, 1024, 1024, 2048, bffn, nullptr, 0.0f);
}

// Round 6
// 882.699 us; speedup vs baseline: 1.3059x; 1.0560x over previous
//
#include <hip/hip_runtime.h>
#include <cstdint>

typedef _Float16 f16;
typedef __attribute__((ext_vector_type(8))) _Float16 f16x8;
typedef __attribute__((ext_vector_type(4))) _Float16 f16x4;
typedef __attribute__((ext_vector_type(4))) float f32x4;

#define NROIS 4096
#define NBANK 8192
#define DIMIN 2048
#define LAT   1024

__device__ __forceinline__ void gload16(const f16* g, f16* l) {
  __builtin_amdgcn_global_load_lds(
      (const __attribute__((address_space(1))) void*)g,
      (__attribute__((address_space(3))) void*)l, 16, 0, 0);
}

__device__ __forceinline__ f32x4 mfma16(f16x8 a, f16x8 b, f32x4 c) {
  return __builtin_amdgcn_mfma_f32_16x16x32_f16(a, b, c, 0, 0, 0);
}

// ---------------------------------------------------------------------------
// 256x256 tile, BK=32, 512 threads (8 waves 2Mx4N). v3 = R4 skeleton
// (4-slot LDS rotation, counted vmcnt(4), T2 swizzle, XCD swizzle) + 2-phase
// interleave per K-tile:
//   P1: {ds_read af[0..3],bf[0..3] | stage A(t+2) | 16 MFMA} barrier
//   P2: {ds_read af[4..7]          | stage B(t+2) | 16 MFMA} vmcnt(4) barrier
// Safety: reads slot t&3, stages slot (t+2)&3; barrier bounds skew to 1 phase
// -> concurrent LDS regions always disjoint mod 4. vmcnt(4) completes tile
// t+1's 4 loads (issued one full iter earlier -> latency hidden).
// MODE 0: C f16 = acc + bias[col]
// MODE 1: C f16 = exp(acc*scale); den[row] += row-sum (atomic)
// MODE 2: C f32 atomicAdd(acc)  (split-K via blockIdx.z)
// MODE 4: batched PV: br = z>>zlog, sp = z&((1<<zlog)-1); runtime strides.
// ---------------------------------------------------------------------------
template<int MODE>
__global__ __launch_bounds__(512, 1)
void gemm2(const f16* __restrict__ A, const f16* __restrict__ B,
           void* __restrict__ Cp, int K, int lda, int ldb, int ldc,
           const float* __restrict__ bias, float* __restrict__ den,
           float scale, int zlog,
           unsigned long long aBstr, unsigned long long bBstr,
           unsigned long long cBstr)
{
  extern __shared__ __align__(16) f16 lds[];   // [4][8192] A | [4][8192] B
  f16* As = lds;
  f16* Bs = lds + 4 * 8192;

  const int tid  = threadIdx.x;
  const int w    = tid >> 6;
  const int lane = tid & 63;

  int br = 0, sp = blockIdx.z;
  if (MODE == 4) { br = blockIdx.z >> zlog; sp = blockIdx.z & ((1 << zlog) - 1); }
  const f16* Abase_g = A;
  const f16* Bbase_g = B;
  if (MODE == 4) { Abase_g += (size_t)br * aBstr; Bbase_g += (size_t)br * bBstr; }

  // XCD swizzle (bijective: gx*gy % 8 == 0 for all our launches)
  const int gx = gridDim.x;
  const int nwg = gx * gridDim.y;
  int id = blockIdx.y * gx + blockIdx.x;
  id = (id & 7) * (nwg >> 3) + (id >> 3);
  const int bx = id % gx, by = id / gx;

  const int r0   = by * 256;
  const int c0   = bx * 256;
  const int koff = sp * K;

  // staging: dest = LDS row (tid>>2), chunk (tid&3); source chunk swizzled
  const int rr = tid >> 2;
  const int ci = (tid & 3) ^ ((tid >> 3) & 3);
  const f16* gA = Abase_g + (size_t)(r0 + rr) * lda + koff + ci * 8;
  const f16* gB = Bbase_g + (size_t)(c0 + rr) * ldb + koff + ci * 8;
  const size_t lda128 = (size_t)128 * lda;
  const size_t ldb128 = (size_t)128 * ldb;
  f16* dA = As + tid * 8;
  f16* dB = Bs + tid * 8;

  // fragment read offsets (swizzled k-chunk, row-dependent part is lane-only)
  const int swz  = ((lane >> 4) ^ ((lane >> 1) & 3)) * 8;
  const int aoff = ((w >> 2) * 128 + (lane & 15)) * 32 + swz;
  const int boff = ((w & 3) * 64 + (lane & 15)) * 32 + swz;

  f32x4 acc[8][4];
#pragma unroll
  for (int m = 0; m < 8; ++m)
#pragma unroll
    for (int n = 0; n < 4; ++n)
      acc[m][n] = (f32x4)0.0f;

  const int nt = K >> 5;

  // prologue: stage tiles 0 (slot 0) and 1 (slot 1)
  gload16(gA,               dA);
  gload16(gA + lda128,      dA + 4096);
  gload16(gB,               dB);
  gload16(gB + ldb128,      dB + 4096);
  gload16(gA + 32,          dA + 8192);
  gload16(gA + 32 + lda128, dA + 8192 + 4096);
  gload16(gB + 32,          dB + 8192);
  gload16(gB + 32 + ldb128, dB + 8192 + 4096);
  asm volatile("s_waitcnt vmcnt(4)" ::: "memory");   // tile 0 resident
  __builtin_amdgcn_s_barrier();
  __builtin_amdgcn_sched_barrier(0);

  for (int t = 0; t < nt; ++t) {
    const int s = (t & 3) * 8192;
    const f16* Ab = As + s + aoff;
    const f16* Bb = Bs + s + boff;
    const bool pf = (t + 2) < nt;
    const int ps = ((t + 2) & 3) * 8192;
    const f16* gAt = gA + (size_t)(t + 2) * 32;
    const f16* gBt = gB + (size_t)(t + 2) * 32;

    // ---- phase 1: read af[0..3]+bf | stage A(t+2) | MFMA m0-3 ----
    f16x8 af[4], bf[4];
#pragma unroll
    for (int n = 0; n < 4; ++n) bf[n] = *(const f16x8*)(Bb + n * 512);
#pragma unroll
    for (int m = 0; m < 4; ++m) af[m] = *(const f16x8*)(Ab + m * 512);
    if (pf) {
      gload16(gAt,          dA + ps);
      gload16(gAt + lda128, dA + ps + 4096);
    }
    __builtin_amdgcn_s_setprio(1);
#pragma unroll
    for (int m = 0; m < 4; ++m)
#pragma unroll
      for (int n = 0; n < 4; ++n)
        acc[m][n] = mfma16(af[m], bf[n], acc[m][n]);
    __builtin_amdgcn_s_setprio(0);
    __builtin_amdgcn_sched_barrier(0);
    __builtin_amdgcn_s_barrier();           // mid barrier (phase lock)
    __builtin_amdgcn_sched_barrier(0);

    // ---- phase 2: read af[4..7] | stage B(t+2) | MFMA m4-7 ----
#pragma unroll
    for (int m = 0; m < 4; ++m) af[m] = *(const f16x8*)(Ab + (m + 4) * 512);
    if (pf) {
      gload16(gBt,          dB + ps);
      gload16(gBt + ldb128, dB + ps + 4096);
    }
    __builtin_amdgcn_s_setprio(1);
#pragma unroll
    for (int m = 0; m < 4; ++m)
#pragma unroll
      for (int n = 0; n < 4; ++n)
        acc[m + 4][n] = mfma16(af[m], bf[n], acc[m + 4][n]);
    __builtin_amdgcn_s_setprio(0);
    __builtin_amdgcn_sched_barrier(0);
    if (pf) asm volatile("s_waitcnt vmcnt(4)" ::: "memory");  // t+1 resident
    else    asm volatile("s_waitcnt vmcnt(0)" ::: "memory");
    __builtin_amdgcn_s_barrier();           // tile boundary
    __builtin_amdgcn_sched_barrier(0);
  }

  // epilogue. C/D layout: col = lane&15, row = (lane>>4)*4 + j
  const int cr = (lane >> 4) * 4;
  const int cc = lane & 15;
  const int wrow = (w >> 2) * 128;
  const int wcol = (w & 3) * 64;

  if (MODE == 0) {
    f16* C = (f16*)Cp;
    float bv[4];
#pragma unroll
    for (int n = 0; n < 4; ++n) bv[n] = bias[c0 + wcol + n * 16 + cc];
#pragma unroll
    for (int m = 0; m < 8; ++m)
#pragma unroll
      for (int j = 0; j < 4; ++j) {
        const int r = r0 + wrow + m * 16 + cr + j;
#pragma unroll
        for (int n = 0; n < 4; ++n) {
          const int c = c0 + wcol + n * 16 + cc;
          C[(size_t)r * ldc + c] = (f16)(acc[m][n][j] + bv[n]);
        }
      }
  } else if (MODE == 1) {
    f16* C = (f16*)Cp;
#pragma unroll
    for (int m = 0; m < 8; ++m)
#pragma unroll
      for (int j = 0; j < 4; ++j) {
        const int r = r0 + wrow + m * 16 + cr + j;
        float rs = 0.0f;
#pragma unroll
        for (int n = 0; n < 4; ++n) {
          const int c = c0 + wcol + n * 16 + cc;
          float e = __expf(acc[m][n][j] * scale);
          rs += e;
          C[(size_t)r * ldc + c] = (f16)e;
        }
        rs += __shfl_xor(rs, 1);
        rs += __shfl_xor(rs, 2);
        rs += __shfl_xor(rs, 4);
        rs += __shfl_xor(rs, 8);
        if (cc == 0) unsafeAtomicAdd(&den[r], rs);
      }
  } else {  // MODE 2 / MODE 4: f32 atomic accumulate
    float* C = (float*)Cp;
    if (MODE == 4) C += (size_t)br * cBstr;
#pragma unroll
    for (int m = 0; m < 8; ++m)
#pragma unroll
      for (int j = 0; j < 4; ++j) {
        const int r = r0 + wrow + m * 16 + cr + j;
#pragma unroll
        for (int n = 0; n < 4; ++n) {
          const int c = c0 + wcol + n * 16 + cc;
          unsafeAtomicAdd(&C[(size_t)r * ldc + c], acc[m][n][j]);
        }
      }
  }
}

// ---------------------------------------------------------------------------
// 128x128 / BK=32 template + T2 swizzle -- used for q12 and FFN
// ---------------------------------------------------------------------------
template<int MODE>
__global__ __launch_bounds__(256)
void gemm_bt(const f16* __restrict__ A, const f16* __restrict__ B,
             void* __restrict__ Cp, int K, int lda, int ldb, int ldc,
             const float* __restrict__ bias)
{
  __shared__ __align__(16) f16 As[128 * 32];
  __shared__ __align__(16) f16 Bs[128 * 32];
  const int t    = threadIdx.x;
  const int w    = t >> 6;
  const int lane = t & 63;
  const int r0   = blockIdx.y * 128;
  const int c0   = blockIdx.x * 128;

  const int lr = lane >> 2;
  const int lc = ((lane & 3) ^ ((lane >> 3) & 3)) * 8; // swizzled source chunk

  f32x4 acc[4][4];
#pragma unroll
  for (int m = 0; m < 4; ++m)
#pragma unroll
    for (int n = 0; n < 4; ++n)
      acc[m][n] = (f32x4)0.0f;

  const int wr = (w >> 1) * 64;
  const int wc = (w & 1) * 64;
  const int fr = lane & 15;
  const int fs = ((lane >> 4) ^ ((lane >> 1) & 3)) * 8; // swizzled read chunk

  for (int k0 = 0; k0 < K; k0 += 32) {
#pragma unroll
    for (int i = 0; i < 2; ++i) {
      const int ch = i * 4 + w;
      gload16(A + (size_t)(r0 + ch * 16 + lr) * lda + (k0 + lc),
              &As[ch * 512 + lane * 8]);
      gload16(B + (size_t)(c0 + ch * 16 + lr) * ldb + (k0 + lc),
              &Bs[ch * 512 + lane * 8]);
    }
    __syncthreads();

    f16x8 af[4], bfv[4];
#pragma unroll
    for (int m = 0; m < 4; ++m)
      af[m] = *(const f16x8*)&As[(wr + m * 16 + fr) * 32 + fs];
#pragma unroll
    for (int n = 0; n < 4; ++n)
      bfv[n] = *(const f16x8*)&Bs[(wc + n * 16 + fr) * 32 + fs];
#pragma unroll
    for (int m = 0; m < 4; ++m)
#pragma unroll
      for (int n = 0; n < 4; ++n)
        acc[m][n] = mfma16(af[m], bfv[n], acc[m][n]);
    __syncthreads();
  }

  const int cr = (lane >> 4) * 4;
  const int cc = lane & 15;

  if (MODE == 0) {
    f16* C = (f16*)Cp;
#pragma unroll
    for (int m = 0; m < 4; ++m)
#pragma unroll
      for (int j = 0; j < 4; ++j) {
        const int r = r0 + wr + m * 16 + cr + j;
#pragma unroll
        for (int n = 0; n < 4; ++n) {
          const int c = c0 + wc + n * 16 + cc;
          C[(size_t)r * ldc + c] = (f16)(acc[m][n][j] + bias[c]);
        }
      }
  } else {
    float* C = (float*)Cp;
#pragma unroll
    for (int m = 0; m < 4; ++m)
#pragma unroll
      for (int j = 0; j < 4; ++j) {
        const int r = r0 + wr + m * 16 + cr + j;
#pragma unroll
        for (int n = 0; n < 4; ++n) {
          const int c = c0 + wc + n * 16 + cc;
          C[(size_t)r * ldc + c] = acc[m][n][j] + bias[c];
        }
      }
  }
}

// multi-segment f32 -> f16 convert: one launch for all 9 conversions
struct CvtSeg { const float* src; f16* dst; int n4; };
struct CvtArgs { CvtSeg s[9]; int tot4; };

__global__ __launch_bounds__(256)
void cvt_multi(CvtArgs a) {
  int i = blockIdx.x * 256 + threadIdx.x;
  const int stride = gridDim.x * 256;
  for (; i < a.tot4; i += stride) {
    int j = i, k = 0;
    while (j >= a.s[k].n4) { j -= a.s[k].n4; ++k; }
    float4 v = ((const float4*)a.s[k].src)[j];
    f16x4 o = { (f16)v.x, (f16)v.y, (f16)v.z, (f16)v.w };
    ((f16x4*)a.s[k].dst)[j] = o;
  }
}

__global__ __launch_bounds__(256)
void init_misc(const float* __restrict__ bc1, const float* __restrict__ bd1,
               const float* __restrict__ bc2, const float* __restrict__ bc3,
               const float* __restrict__ bd2, const float* __restrict__ bd3,
               float* __restrict__ biasq, float* __restrict__ biaskv,
               float* __restrict__ den)
{
  const int i = blockIdx.x * 256 + threadIdx.x;
  if (i < 1024) {
    biasq[i]         = bc1[i];
    biasq[1024 + i]  = bd1[i];
    biaskv[i]        = bc2[i];
    biaskv[1024 + i] = bc3[i];
    biaskv[2048 + i] = bd2[i];
    biaskv[3072 + i] = bd3[i];
  }
  den[i] = 0.0f;
}

__global__ __launch_bounds__(256)
void zero_f32(float4* __restrict__ p, int n4) {
  int i = blockIdx.x * 256 + threadIdx.x;
  const int stride = gridDim.x * 256;
  float4 z; z.x = 0.f; z.y = 0.f; z.z = 0.f; z.w = 0.f;
  for (; i < n4; i += stride) p[i] = z;
}

__global__ __launch_bounds__(256)
void fill_f32(float* __restrict__ p, float v, int n) {
  int i = blockIdx.x * 256 + threadIdx.x;
  const int stride = gridDim.x * 256;
  for (; i < n; i += stride) p[i] = v;
}

// vT[c][r] = kv[r][col_ofs + c]   (r<8192, c<1024), 64x64 LDS tiles
__global__ __launch_bounds__(256)
void transpose_v(const f16* __restrict__ kv, f16* __restrict__ vT, int col_ofs) {
  __shared__ f16 tile[64][66];
  const int r0 = blockIdx.x * 64;
  const int c0 = blockIdx.y * 64;
  const int tx = threadIdx.x;
  const int ty = threadIdx.y;
  for (int i = ty; i < 64; i += 4)
    tile[i][tx] = kv[(size_t)(r0 + i) * 4096 + col_ofs + c0 + tx];
  __syncthreads();
  for (int i = ty; i < 64; i += 4)
    vT[(size_t)(c0 + i) * NBANK + r0 + tx] = tile[tx][i];
}

// cpair = (f1/den1)*(f2/den2); LayerNorm over 1024; PReLU; -> x f16
__global__ __launch_bounds__(256)
void gate_ln(const float* __restrict__ f1, const float* __restrict__ f2,
             const float* __restrict__ den,
             const float* __restrict__ lnw, const float* __restrict__ lnb,
             const float* __restrict__ pa, f16* __restrict__ x)
{
  const int row = blockIdx.x;
  const int t   = threadIdx.x;
  const int lane = t & 63, w = t >> 6;
  const float inv1 = 1.0f / den[row];
  const float inv2 = 1.0f / den[NROIS + row];
  const float4 a = ((const float4*)(f1 + (size_t)row * LAT))[t];
  const float4 b = ((const float4*)(f2 + (size_t)row * LAT))[t];
  float c[4] = { a.x * b.x * inv1 * inv2, a.y * b.y * inv1 * inv2,
                 a.z * b.z * inv1 * inv2, a.w * b.w * inv1 * inv2 };
  float s = c[0] + c[1] + c[2] + c[3];
  float q = c[0]*c[0] + c[1]*c[1] + c[2]*c[2] + c[3]*c[3];
#pragma unroll
  for (int m = 1; m < 64; m <<= 1) {
    s += __shfl_xor(s, m);
    q += __shfl_xor(q, m);
  }
  __shared__ float red[8];
  if (lane == 0) { red[w] = s; red[4 + w] = q; }
  __syncthreads();
  s = red[0] + red[1] + red[2] + red[3];
  q = red[4] + red[5] + red[6] + red[7];
  const float mu  = s * (1.0f / LAT);
  const float var = q * (1.0f / LAT) - mu * mu;
  const float rs  = rsqrtf(var + 1e-5f);
  const float slope = pa[0];
  f16x4 o;
#pragma unroll
  for (int j = 0; j < 4; ++j) {
    float xv = (c[j] - mu) * rs * lnw[t * 4 + j] + lnb[t * 4 + j];
    xv = (xv >= 0.0f) ? xv : slope * xv;
    o[j] = (f16)xv;
  }
  ((f16x4*)(x + (size_t)row * LAT))[t] = o;
}

extern "C" void kernel_launch(void* const* d_in, const int* in_sizes, int n_in,
                              void* d_out, int out_size, void* d_ws, size_t ws_size,
                              hipStream_t stream) {
  const float* feat = (const float*)d_in[0];
  const float* bank = (const float*)d_in[1];
  const float* Wc1  = (const float*)d_in[2];
  const float* bc1  = (const float*)d_in[3];
  const float* Wc2  = (const float*)d_in[4];
  const float* bc2  = (const float*)d_in[5];
  const float* Wc3  = (const float*)d_in[6];
  const float* bc3  = (const float*)d_in[7];
  const float* Wd1  = (const float*)d_in[8];
  const float* bd1  = (const float*)d_in[9];
  const float* Wd2  = (const float*)d_in[10];
  const float* bd2  = (const float*)d_in[11];
  const float* Wd3  = (const float*)d_in[12];
  const float* bd3  = (const float*)d_in[13];
  const float* lnw  = (const float*)d_in[14];
  const float* lnb  = (const float*)d_in[15];
  const float* pa   = (const float*)d_in[16];
  const float* Wffn = (const float*)d_in[17];
  const float* bffn = (const float*)d_in[18];

  const size_t MBy = 1ull << 20;

  if (ws_size < 133 * MBy) {
    fill_f32<<<dim3(2048), dim3(256), 0, stream>>>((float*)d_out, 12345.0f, out_size);
    return;
  }
  const int tier = (ws_size >= 245 * MBy) ? 2 : (ws_size >= 181 * MBy) ? 1 : 0;

  const int DYN_LDS = 4 * 2 * 8192 * 2;  // 131072 (128 KB)
  (void)hipFuncSetAttribute(reinterpret_cast<const void*>(&gemm2<0>),
                            hipFuncAttributeMaxDynamicSharedMemorySize, DYN_LDS);
  (void)hipFuncSetAttribute(reinterpret_cast<const void*>(&gemm2<1>),
                            hipFuncAttributeMaxDynamicSharedMemorySize, DYN_LDS);
  (void)hipFuncSetAttribute(reinterpret_cast<const void*>(&gemm2<2>),
                            hipFuncAttributeMaxDynamicSharedMemorySize, DYN_LDS);
  (void)hipFuncSetAttribute(reinterpret_cast<const void*>(&gemm2<4>),
                            hipFuncAttributeMaxDynamicSharedMemorySize, DYN_LDS);

  char* ws = (char*)d_ws;
  // persistent
  f16* kvb  = (f16*)(ws);              // [0,64M)   kv = k1|v1|k2|v2
  f16* q12  = (f16*)(ws + 64 * MBy);   // [64,80M)  q1|q2
  f16* Wfb  = (f16*)(ws + 80 * MBy);   // [80,84M)  Wffn f16
  f16* WQ   = (f16*)(ws + 84 * MBy);   // phase1 only
  f16* xbuf = (f16*)(ws + 84 * MBy);   // phase4 (vT/WQ dead by then)
  // d_out doubles as scratch until the final GEMM overwrites it:
  f16*   WKV = (f16*)d_out;                       // [0,16M)  phase1
  f16*   FB  = (f16*)((char*)d_out + 16 * MBy);   // [16,32M) phase1
  float* f1  = (float*)d_out;                     // [0,16M)  phase3
  float* f2  = (float*)((char*)d_out + 16 * MBy); // [16,32M) phase3

  f16 *vT0, *vT1 = nullptr, *E0, *E1 = nullptr, *BB;
  float *biasq, *biaskv, *den;
  size_t tail;
  if (tier == 2) {
    vT0 = (f16*)(ws + 84 * MBy);    // [84,100M)
    vT1 = (f16*)(ws + 100 * MBy);   // [100,116M)
    E0  = (f16*)(ws + 116 * MBy);   // [116,180M)  full [4096x8192]
    E1  = (f16*)(ws + 180 * MBy);   // [180,244M)
    BB  = (f16*)(ws + 116 * MBy);   // phase1 (dead before E0 written)
    tail = 244 * MBy;
  } else if (tier == 1) {
    vT0 = (f16*)(ws + 84 * MBy);
    vT1 = (f16*)(ws + 100 * MBy);
    E0  = (f16*)(ws + 116 * MBy);   // [116,148M)  chunk [2048x8192]
    E1  = (f16*)(ws + 148 * MBy);
    BB  = (f16*)(ws + 116 * MBy);
    tail = 180 * MBy;
  } else {
    vT0 = (f16*)(ws + 84 * MBy);    // per-branch reuse
    E0  = (f16*)(ws + 100 * MBy);   // [100,132M)
    BB  = (f16*)(ws + 92 * MBy);
    tail = 132 * MBy;
  }
  biasq  = (float*)(ws + tail);
  biaskv = (float*)(ws + tail + 8192);
  den    = (float*)(ws + tail + 24576);

  init_misc<<<dim3(32), dim3(256), 0, stream>>>(bc1, bd1, bc2, bc3, bd2, bd3,
                                                biasq, biaskv, den);

  // one fused conversion launch (9 segments)
  {
    CvtArgs a;
    const int W4 = (1024 * 2048) / 4;
    a.s[0] = { Wc1,  WQ,                         W4 };
    a.s[1] = { Wd1,  WQ + (size_t)1024 * 2048,   W4 };
    a.s[2] = { feat, FB,                         (NROIS * DIMIN) / 4 };
    a.s[3] = { Wc2,  WKV,                        W4 };
    a.s[4] = { Wc3,  WKV + (size_t)1024 * 2048,  W4 };
    a.s[5] = { Wd2,  WKV + (size_t)2048 * 2048,  W4 };
    a.s[6] = { Wd3,  WKV + (size_t)3072 * 2048,  W4 };
    a.s[7] = { bank, BB,                         (NBANK * DIMIN) / 4 };
    a.s[8] = { Wffn, Wfb,                        W4 };
    a.tot4 = 7 * W4 + (NROIS * DIMIN) / 4 + (NBANK * DIMIN) / 4;
    cvt_multi<<<dim3(2048), dim3(256), 0, stream>>>(a);
  }

  // q12 = FB @ WQ^T + biasq   [4096,2048]  (128^2 template)
  gemm_bt<0><<<dim3(16, 32, 1), 256, 0, stream>>>(
      FB, WQ, q12, 2048, 2048, 2048, 2048, biasq);
  // kv = BB @ WKV^T + biaskv  [8192,4096]  (256^2 v3)
  gemm2<0><<<dim3(16, 32, 1), 512, DYN_LDS, stream>>>(
      BB, WKV, kvb, 2048, 2048, 2048, 4096, biaskv, nullptr, 0.0f, 0, 0, 0, 0);

  // zero f1,f2 (all of d_out) -- FB/WKV dead now
  zero_f32<<<dim3(2048), dim3(256), 0, stream>>>((float4*)d_out, (32 * (int)MBy) / 16);

  const float scl = 0.03125f;  // 1/sqrt(1024)
  if (tier == 2) {
    transpose_v<<<dim3(128, 16, 1), dim3(64, 4), 0, stream>>>(kvb, vT0, 1024);
    transpose_v<<<dim3(128, 16, 1), dim3(64, 4), 0, stream>>>(kvb, vT1, 3072);
    // E_b = exp(q_b @ k_b^T / 32)  [4096,8192] f16 + row sums  (512 blocks ea)
    gemm2<1><<<dim3(32, 16, 1), 512, DYN_LDS, stream>>>(
        q12, kvb, E0, 1024, 2048, 4096, 8192, nullptr, den, scl, 0, 0, 0, 0);
    gemm2<1><<<dim3(32, 16, 1), 512, DYN_LDS, stream>>>(
        q12 + 1024, kvb + 2048, E1, 1024, 2048, 4096, 8192,
        nullptr, den + NROIS, scl, 0, 0, 0, 0);
    // f1 += E0 @ vT0^T ; f2 += E1 @ vT1^T  in ONE dispatch (split-2, 256 blk)
    gemm2<4><<<dim3(4, 16, 4), 512, DYN_LDS, stream>>>(
        E0, vT0, f1, 4096, 8192, 8192, 1024, nullptr, nullptr, 0.0f,
        1, (size_t)4096 * 8192, (size_t)1024 * 8192, (size_t)4096 * 1024);
  } else if (tier == 1) {
    transpose_v<<<dim3(128, 16, 1), dim3(64, 4), 0, stream>>>(kvb, vT0, 1024);
    transpose_v<<<dim3(128, 16, 1), dim3(64, 4), 0, stream>>>(kvb, vT1, 3072);
    for (int chunk = 0; chunk < 2; ++chunk) {
      const size_t qo = (size_t)chunk * 2048 * 2048;
      gemm2<1><<<dim3(32, 8, 1), 512, DYN_LDS, stream>>>(
          q12 + qo, kvb, E0, 1024, 2048, 4096, 8192,
          nullptr, den + chunk * 2048, scl, 0, 0, 0, 0);
      gemm2<1><<<dim3(32, 8, 1), 512, DYN_LDS, stream>>>(
          q12 + qo + 1024, kvb + 2048, E1, 1024, 2048, 4096, 8192,
          nullptr, den + NROIS + chunk * 2048, scl, 0, 0, 0, 0);
      gemm2<4><<<dim3(4, 8, 8), 512, DYN_LDS, stream>>>(
          E0, vT0, f1 + (size_t)chunk * 2048 * 1024, 2048, 8192, 8192, 1024,
          nullptr, nullptr, 0.0f,
          2, (size_t)2048 * 8192, (size_t)1024 * 8192, (size_t)4096 * 1024);
    }
  } else {
    for (int b = 0; b < 2; ++b) {
      transpose_v<<<dim3(128, 16, 1), dim3(64, 4), 0, stream>>>(
          kvb, vT0, 1024 + b * 2048);
      float* fb = b ? f2 : f1;
      for (int chunk = 0; chunk < 2; ++chunk) {
        gemm2<1><<<dim3(32, 8, 1), 512, DYN_LDS, stream>>>(
            q12 + (size_t)chunk * 2048 * 2048 + b * 1024, kvb + b * 2048,
            E0, 1024, 2048, 4096, 8192,
            nullptr, den + b * NROIS + chunk * 2048, scl, 0, 0, 0, 0);
        gemm2<2><<<dim3(4, 8, 4), 512, DYN_LDS, stream>>>(
            E0, vT0, fb + (size_t)chunk * 2048 * 1024, 2048, 8192, 8192, 1024,
            nullptr, nullptr, 0.0f, 0, 0, 0, 0);
      }
    }
  }

  // gate + LayerNorm + PReLU -> x f16 [4096,1024]
  gate_ln<<<dim3(NROIS), dim3(256), 0, stream>>>(f1, f2, den, lnw, lnb, pa, xbuf);

  // out = x @ Wffn^T + bffn  [4096,2048] f32 (overwrites all of d_out)
  gemm_bt<3><<<dim3(16, 32, 1), 256, 0, stream>>>(
      xbuf, Wfb, (float*)d_out, 1024, 1024, 1024, 2048, bffn);
}